// Round 13
// baseline (1195.164 us; speedup 1.0000x reference)
//
#include <hip/hip_runtime.h>

#define NP_   16384
#define NQ_   8192
#define NB_   2
#define K_    16
#define S32   32           // lanes per query
#define QPB   8            // queries per block (256/32)
#define TPB   256
#define TILE  1024         // points per LDS tile (16KB)
#define NTILES (NP_/TILE)  // 16
#define JPT   (TILE/S32)   // 32 candidates per lane per tile

#define IDX_OFF 0
#define RS_OFF  (NB_*NQ_*K_)        // 262144
#define RS_N    (NB_*NQ_+1)         // 16385
#define DST_OFF (RS_OFF + RS_N)     // 278529

__global__ __launch_bounds__(TPB, 4) void knn_kernel(const float* __restrict__ pts,
                                                     const float* __restrict__ qrs,
                                                     float* __restrict__ out)
{
    // Validated exact-match formula (R6):
    //   sq, sp : forward sum, separate mul/add rounds
    //   ip     : forward FMA chain  fma(z,qz, fma(y,qy, round(x*qx)))
    //   d      : fmaf(-2, ip, sq+sp)   (== (sq+sp)-2*ip bit-exactly)
    #pragma clang fp contract(off)

    __shared__ float4 tile[TILE];   // 16KB LDS -> up to 8 blocks/CU

    const int tid = threadIdx.x;
    const int s   = tid & (S32 - 1);               // 0..31: slice within query
    const int gq  = blockIdx.x * QPB + (tid >> 5); // own query
    const int batch = gq >> 13;
    const int gofs  = batch * NP_;
    const float* pb = pts + (size_t)gofs * 3;

    const float qx = qrs[gq*3+0], qy = qrs[gq*3+1], qz = qrs[gq*3+2];
    const float sq = qx*qx + qy*qy + qz*qz;        // fwd, no FMA (contract off)

    const float INF = __int_as_float(0x7f800000);
    float ad[K_]; int ai[K_];
    #pragma unroll
    for (int i = 0; i < K_; ++i) { ad[i] = INF; ai[i] = 0x7fffffff; }

    auto dOf = [&](int pid) {                      // exact chain, tile-local pid
        float4 p = tile[pid];
        float ip = fmaf(p.z, qz, fmaf(p.y, qy, __fmul_rn(p.x, qx)));
        return fmaf(-2.0f, ip, sq + p.w);
    };

    auto insert1 = [&](float d, int gi) {
        if (d < ad[K_-1]) {                        // strict: stable on ties
            ad[K_-1] = d; ai[K_-1] = gi;
            #pragma unroll
            for (int i = K_-1; i > 0; --i) {
                bool sw = ad[i] < ad[i-1];
                float td = ad[i-1]; int ti = ai[i-1];
                ad[i-1] = sw ? ad[i] : td;  ai[i-1] = sw ? ai[i] : ti;
                ad[i]   = sw ? td   : ad[i]; ai[i]  = sw ? ti   : ai[i];
            }
        }
    };

    auto qmin32 = [&](float w) {                   // min over the query's 32 lanes
        #pragma unroll
        for (int off = 16; off >= 1; off >>= 1)
            w = fminf(w, __shfl_xor(w, off, S32));
        return w;
    };

    float thresh = INF;

    for (int t = 0; t < NTILES; ++t) {
        __syncthreads();
        #pragma unroll
        for (int k = 0; k < TILE/TPB; ++k) {
            int lp = tid + k*TPB;
            int gp = t*TILE + lp;
            float x = pb[gp*3+0], y = pb[gp*3+1], z = pb[gp*3+2];
            float sp = x*x + y*y + z*z;            // fwd, no FMA
            tile[lp] = make_float4(x, y, z, sp);
        }
        __syncthreads();

        int j0 = 0;
        if (t == 0) {                              // seed: 16 uniform inserts
            for (int j = 0; j < K_; ++j)
                insert1(dOf(j*S32 + s), j*S32 + s);
            thresh = qmin32(ad[K_-1]);             // finite now
            j0 = K_;
        }

        #pragma unroll 4
        for (int j = j0; j < JPT; ++j) {
            int pid = j*S32 + s;
            float d = dOf(pid);
            bool pass = d <= thresh;               // filter key == final key
            if (__any(pass)) {                     // rare: scalar skip
                if (pass) insert1(d, t*TILE + pid);
            }
        }

        thresh = qmin32(ad[K_-1]);
    }

    // ---- register-only extraction merge: 32 sorted lists -> global top-16 ----
    float rd = 0.0f; int ri = 0;
    for (int r = 0; r < K_; ++r) {
        float bd = ad[0]; int bi = ai[0]; int bl = s;
        #pragma unroll
        for (int off = 16; off >= 1; off >>= 1) {
            float od = __shfl_xor(bd, off, S32);
            int   oi = __shfl_xor(bi, off, S32);
            int   ol = __shfl_xor(bl, off, S32);
            bool take = (od < bd) || (od == bd && oi < bi);   // lexicographic
            bd = take ? od : bd; bi = take ? oi : bi; bl = take ? ol : bl;
        }
        if (r == s) { rd = bd; ri = bi; }          // lane r keeps rank-r
        if (bl == s) {                             // winner pops its head: shift
            #pragma unroll
            for (int i = 0; i < K_-1; ++i) { ad[i] = ad[i+1]; ai[i] = ai[i+1]; }
            ad[K_-1] = INF; ai[K_-1] = 0x7fffffff;
        }
    }

    if (s < K_) {                                  // lane s writes rank-s
        out[IDX_OFF + gq*K_ + s] = (float)(ri + gofs);
        out[DST_OFF + gq*K_ + s] = fmaxf(rd, 0.0f);
    }

    // row_splits = arange(16385) * 16, written as float (exact)
    int gt = blockIdx.x * TPB + tid;
    if (gt < RS_N) out[RS_OFF + gt] = (float)(gt * K_);
}

extern "C" void kernel_launch(void* const* d_in, const int* in_sizes, int n_in,
                              void* d_out, int out_size, void* d_ws, size_t ws_size,
                              hipStream_t stream)
{
    const float* pts = (const float*)d_in[0];
    const float* qrs = (const float*)d_in[1];
    float* out = (float*)d_out;
    (void)in_sizes; (void)n_in; (void)out_size; (void)d_ws; (void)ws_size;

    dim3 grid(NB_ * NQ_ / QPB);   // 2048 blocks = 8 blocks/CU
    dim3 block(TPB);              // 256 threads
    knn_kernel<<<grid, block, 0, stream>>>(pts, qrs, out);
}

// Round 14
// 185.189 us; speedup vs baseline: 6.4537x; 6.4537x over previous
//
#include <hip/hip_runtime.h>

#define NP_   16384
#define NQ_   8192
#define NB_   2
#define K_    16
#define QPB   16           // queries per block (4 per wave x 4 waves)
#define TPB   256
#define TILE  1024         // points per LDS tile (16KB)
#define NTILES (NP_/TILE)  // 16
#define GPT   (TILE/64)    // 16 point-group iterations per tile

#define IDX_OFF 0
#define RS_OFF  (NB_*NQ_*K_)        // 262144
#define RS_N    (NB_*NQ_+1)         // 16385
#define DST_OFF (RS_OFF + RS_N)     // 278529

typedef unsigned long long ull;

__global__ __launch_bounds__(TPB, 4) void knn_kernel(const float* __restrict__ pts,
                                                     const float* __restrict__ qrs,
                                                     float* __restrict__ out)
{
    // Validated exact-match formula (R6):
    //   sq, sp : forward sum, separate mul/add rounds
    //   ip     : forward FMA chain  fma(z,qz, fma(y,qy, round(x*qx)))
    //   d      : fmaf(-2, ip, sq+sp)
    // The scanned d is inserted AS-IS (shuffled, never recomputed) -> exact.
    #pragma clang fp contract(off)

    __shared__ float4 tile[TILE];   // 16KB

    const int tid  = threadIdx.x;
    const int lane = tid & 63;
    const int s    = lane & 15;               // rank this lane owns
    const int gq   = blockIdx.x * QPB + (tid >> 4);   // lane's own query
    const int batch = gq >> 13;
    const int gofs  = batch * NP_;
    const float* pb = pts + (size_t)gofs * 3;

    // the wave's 4 queries (register-resident)
    const int qbase = blockIdx.x * QPB + ((tid >> 6) << 2);
    float qxv[4], qyv[4], qzv[4], sqv[4];
    #pragma unroll
    for (int qi = 0; qi < 4; ++qi) {
        qxv[qi] = qrs[(qbase+qi)*3+0];
        qyv[qi] = qrs[(qbase+qi)*3+1];
        qzv[qi] = qrs[(qbase+qi)*3+2];
        sqv[qi] = qxv[qi]*qxv[qi] + qyv[qi]*qyv[qi] + qzv[qi]*qzv[qi];  // fwd, no FMA
    }

    const float INF = __int_as_float(0x7f800000);
    float hd = INF; int hi = 0x7fffffff;      // distributed top-16: rank-s of own query
    float th0 = INF, th1 = INF, th2 = INF, th3 = INF;
    const ull gmask = 0xFFFFull << (lane & 48);

    // one event: insert (dstar from src lane L) into group q's distributed list
    auto process = [&](ull bq, float dq, int q, int base) {
        while (bq) {
            int L = (int)__ffsll(bq) - 1;
            bq &= bq - 1;
            float dstar = __shfl(dq, L);          // value-exact transport
            int   istar = base + L;
            if ((lane >> 4) == q) {               // group q's 16 lanes insert
                ull bb = __ballot(hd <= dstar);   // ties: existing (lower idx) first
                int pos = __popcll(bb & gmask);
                float sd = __shfl_up(hd, 1, 16);
                int   si = __shfl_up(hi, 1, 16);
                if (pos < K_) {                   // pos==16: stale event, drop
                    if (s == pos)      { hd = dstar; hi = istar; }
                    else if (s > pos)  { hd = sd;    hi = si;    }
                }
            }
        }
    };

    for (int t = 0; t < NTILES; ++t) {
        __syncthreads();
        #pragma unroll
        for (int k = 0; k < TILE/TPB; ++k) {
            int lp = tid + k*TPB;
            int gp = t*TILE + lp;
            float x = pb[gp*3+0], y = pb[gp*3+1], z = pb[gp*3+2];
            float sp = x*x + y*y + z*z;           // fwd, no FMA
            tile[lp] = make_float4(x, y, z, sp);
        }
        __syncthreads();

        #pragma unroll 2
        for (int g = 0; g < GPT; ++g) {
            float4 p = tile[g*64 + lane];         // 64 distinct points: full LDS width
            float ip0 = fmaf(p.z, qzv[0], fmaf(p.y, qyv[0], __fmul_rn(p.x, qxv[0])));
            float ip1 = fmaf(p.z, qzv[1], fmaf(p.y, qyv[1], __fmul_rn(p.x, qxv[1])));
            float ip2 = fmaf(p.z, qzv[2], fmaf(p.y, qyv[2], __fmul_rn(p.x, qxv[2])));
            float ip3 = fmaf(p.z, qzv[3], fmaf(p.y, qyv[3], __fmul_rn(p.x, qxv[3])));
            float d0 = fmaf(-2.0f, ip0, sqv[0] + p.w);
            float d1 = fmaf(-2.0f, ip1, sqv[1] + p.w);
            float d2 = fmaf(-2.0f, ip2, sqv[2] + p.w);
            float d3 = fmaf(-2.0f, ip3, sqv[3] + p.w);
            ull b0 = __ballot(d0 < th0);          // strict <: exact selection rule
            ull b1 = __ballot(d1 < th1);
            ull b2 = __ballot(d2 < th2);
            ull b3 = __ballot(d3 < th3);
            if (b0 | b1 | b2 | b3) {              // uniform scalar skip (~60-90%)
                int base = t*TILE + g*64;
                process(b0, d0, 0, base);
                process(b1, d1, 1, base);
                process(b2, d2, 2, base);
                process(b3, d3, 3, base);
                th0 = __shfl(hd, 15);             // true 16th-best per query
                th1 = __shfl(hd, 31);
                th2 = __shfl(hd, 47);
                th3 = __shfl(hd, 63);
            }
        }
    }

    // output: lane s already holds rank-s of its query (no merge needed)
    out[IDX_OFF + gq*K_ + s] = (float)(hi + gofs);
    out[DST_OFF + gq*K_ + s] = fmaxf(hd, 0.0f);

    // row_splits = arange(16385) * 16, written as float (exact)
    int gt = blockIdx.x * TPB + tid;
    if (gt < RS_N) out[RS_OFF + gt] = (float)(gt * K_);
}

extern "C" void kernel_launch(void* const* d_in, const int* in_sizes, int n_in,
                              void* d_out, int out_size, void* d_ws, size_t ws_size,
                              hipStream_t stream)
{
    const float* pts = (const float*)d_in[0];
    const float* qrs = (const float*)d_in[1];
    float* out = (float*)d_out;
    (void)in_sizes; (void)n_in; (void)out_size; (void)d_ws; (void)ws_size;

    dim3 grid(NB_ * NQ_ / QPB);   // 1024 blocks
    dim3 block(TPB);              // 256 threads
    knn_kernel<<<grid, block, 0, stream>>>(pts, qrs, out);
}